// Round 10
// baseline (227.710 us; speedup 1.0000x reference)
//
#include <hip/hip_runtime.h>
#include <cstdint>

#define N_NODES 100000
#define N_PAD 100096   // padded row capacity (multiple of 128)
#define N_EDGES 600000
#define F 128
#define CLS 16
#define CAP 64         // max neighbors stored per node (Poisson(6): P(>=64) ~ 1e-40)

typedef short bf16x8 __attribute__((ext_vector_type(8)));
typedef float f32x4 __attribute__((ext_vector_type(4)));
typedef float f32x2 __attribute__((ext_vector_type(2)));

__device__ inline float bf2f(unsigned int lo16) { return __uint_as_float(lo16 << 16); }
__device__ inline unsigned short f2b(float f) {
    unsigned int u = __float_as_uint(f);
    return (unsigned short)((u + 0x7fffu + ((u >> 16) & 1u)) >> 16);
}

// ---------------- init: zero deg + cast x->bf16 & fp8 + weight prep (frag order) ----------------
__global__ __launch_bounds__(256) void init_k(int* __restrict__ deg,
                                              const float* __restrict__ x,
                                              unsigned short* __restrict__ xb,
                                              unsigned int* __restrict__ xf8,
                                              const float* __restrict__ W1l,
                                              const float* __restrict__ W1r,
                                              const float* __restrict__ W2l,
                                              const float* __restrict__ W2r,
                                              unsigned short* __restrict__ w1t,
                                              unsigned short* __restrict__ w2t) {
    int b = blockIdx.x;
    if (b < 98) {
        int i = b * 1024 + threadIdx.x * 4;
#pragma unroll
        for (int k = 0; k < 4; k++)
            if (i + k < N_NODES) deg[i + k] = 0;
    } else if (b < 12598) {
        int i = (b - 98) * 256 + threadIdx.x;
        if (i < N_NODES * F / 4) {
            float4 v = ((const float4*)x)[i];
            ushort4 o;
            o.x = f2b(v.x); o.y = f2b(v.y); o.z = f2b(v.z); o.w = f2b(v.w);
            ((ushort4*)xb)[i] = o;
            int p8 = __builtin_amdgcn_cvt_pk_fp8_f32(v.x, v.y, 0, false);
            p8 = __builtin_amdgcn_cvt_pk_fp8_f32(v.z, v.w, p8, true);
            xf8[i] = (unsigned int)p8;
        }
    } else if (b < 12726) {
        int idx = (b - 12598) * 256 + threadIdx.x;  // 32768: (n,k) n<128, k<256
        int n = idx >> 8, k = idx & 255;
        float v = (k < F) ? W1l[k * F + n] : W1r[(k - F) * F + n];
        int ct = n >> 4, m = n & 15;
        int half = k >> 7, ks = (k >> 5) & 3, quad = (k >> 3) & 3, j = k & 7;
        w1t[(ct * 8 + ks * 2 + half) * 512 + (quad * 16 + m) * 8 + j] = f2b(v);
    } else {
        int idx = (b - 12726) * 256 + threadIdx.x;  // 4096: (n,k) n<32, k<128
        if (idx < 32 * F) {
            int n = idx >> 7, k = idx & 127;
            float v = (n < CLS) ? W2l[k * CLS + n] : W2r[k * CLS + (n - CLS)];
            int tile = n >> 4, m = n & 15;
            int ks = (k >> 5) & 3, quad = (k >> 3) & 3, j = k & 7;
            w2t[(tile * 4 + ks) * 512 + (quad * 16 + m) * 8 + j] = f2b(v);
        }
    }
}

// ---------------- fill: histogram + bucket append in one pass ----------------
__global__ void fill_k(const int* __restrict__ src, const int* __restrict__ dst,
                       int* __restrict__ deg, int* __restrict__ bucket) {
    int e = blockIdx.x * blockDim.x + threadIdx.x;
    if (e < N_EDGES) {
        int d = dst[e];
        int slot = atomicAdd(&deg[d], 1);
        if (slot < CAP) bucket[d * CAP + slot] = src[e];
    }
}

// ---------------- layer-1 mean aggregation: fp8 rows (128B), speculative issue ----------------
__global__ __launch_bounds__(256) void agg_b_k(const unsigned char* __restrict__ feat8,
                                               const int* __restrict__ deg,
                                               const int* __restrict__ bucket,
                                               unsigned short* __restrict__ outagg) {
    int node = blockIdx.x * 4 + (threadIdx.x >> 6);
    int lane = threadIdx.x & 63;
    int r = lane >> 4;
    int f8 = (lane & 15) * 8;   // feature base (1 byte per feature)
    const int* bk = bucket + node * CAP;

    int d_raw = deg[node];
    int nb0 = min(max(bk[r], 0), N_NODES - 1);
    int nb1 = min(max(bk[4 + r], 0), N_NODES - 1);
    uint2 v0 = *(const uint2*)(feat8 + (size_t)nb0 * F + f8);
    uint2 v1 = *(const uint2*)(feat8 + (size_t)nb1 * F + f8);

    int d = min(d_raw, CAP);
    float acc[8] = {0.f, 0.f, 0.f, 0.f, 0.f, 0.f, 0.f, 0.f};
#define ACC8(vv) { f32x2 p; \
    p = __builtin_amdgcn_cvt_pk_f32_fp8((int)(vv).x, false); acc[0] += p.x; acc[1] += p.y; \
    p = __builtin_amdgcn_cvt_pk_f32_fp8((int)(vv).x, true);  acc[2] += p.x; acc[3] += p.y; \
    p = __builtin_amdgcn_cvt_pk_f32_fp8((int)(vv).y, false); acc[4] += p.x; acc[5] += p.y; \
    p = __builtin_amdgcn_cvt_pk_f32_fp8((int)(vv).y, true);  acc[6] += p.x; acc[7] += p.y; }
    if (r < d) ACC8(v0);
    if (4 + r < d) ACC8(v1);
    // rare tail: d > 8
    for (int j = 8; j < d; j += 8) {
        int i0 = j + r, i1 = j + 4 + r;
        bool ok0 = i0 < d, ok1 = i1 < d;
        int m0 = bk[ok0 ? i0 : 0];
        int m1 = bk[ok1 ? i1 : 0];
        uint2 w0 = *(const uint2*)(feat8 + (size_t)m0 * F + f8);
        uint2 w1 = *(const uint2*)(feat8 + (size_t)m1 * F + f8);
        if (ok0) ACC8(w0);
        if (ok1) ACC8(w1);
    }
#undef ACC8
#pragma unroll
    for (int i = 0; i < 8; i++) {
        acc[i] += __shfl_xor(acc[i], 16);
        acc[i] += __shfl_xor(acc[i], 32);
    }
    if (r == 0) {
        float inv = 1.0f / fmaxf((float)d, 1.0f);
        uint4 o;
        o.x = (unsigned int)f2b(acc[0] * inv) | ((unsigned int)f2b(acc[1] * inv) << 16);
        o.y = (unsigned int)f2b(acc[2] * inv) | ((unsigned int)f2b(acc[3] * inv) << 16);
        o.z = (unsigned int)f2b(acc[4] * inv) | ((unsigned int)f2b(acc[5] * inv) << 16);
        o.w = (unsigned int)f2b(acc[6] * inv) | ((unsigned int)f2b(acc[7] * inv) << 16);
        *(uint4*)(outagg + (size_t)node * F + f8) = o;
    }
}

// ---------------- FUSED GEMM: H=relu(A@W1l+X@W1r+b1); trL(bf16)=H@W2l, trR(f32)=H@W2r ----------------
__global__ __launch_bounds__(256) void gemm_fused(const unsigned short* __restrict__ Ab,
                                                  const unsigned short* __restrict__ Xb,
                                                  const unsigned short* __restrict__ Wt,
                                                  const float* __restrict__ bias,
                                                  const unsigned short* __restrict__ Wt2,
                                                  unsigned short* __restrict__ trLb,
                                                  float* __restrict__ trR) {
    __shared__ unsigned short sh[128 * 132];  // H tile, padded
    int tid = threadIdx.x;
    int wave = tid >> 6, lane = tid & 63;
    int row0 = blockIdx.x * 128 + wave * 32;
    int m = lane & 15, quad = lane >> 4;
    int koff = quad * 8;

    const unsigned short* pa0 = Ab + (size_t)(row0 + m) * F + koff;
    const unsigned short* pa1 = pa0 + 16 * F;
    const unsigned short* px0 = Xb + (size_t)(row0 + m) * F + koff;
    const unsigned short* px1 = px0 + 16 * F;
    const unsigned short* pw = Wt + lane * 8;   // + frag*512

    f32x4 acc0[8], acc1[8];
#pragma unroll
    for (int ct = 0; ct < 8; ct++) { acc0[ct] = (f32x4){0,0,0,0}; acc1[ct] = (f32x4){0,0,0,0}; }

#pragma unroll
    for (int ks = 0; ks < 4; ks++) {
        bf16x8 a0 = *(const bf16x8*)(const void*)(pa0 + ks * 32);
        bf16x8 a1 = *(const bf16x8*)(const void*)(pa1 + ks * 32);
        bf16x8 x0 = *(const bf16x8*)(const void*)(px0 + ks * 32);
        bf16x8 x1 = *(const bf16x8*)(const void*)(px1 + ks * 32);
#pragma unroll
        for (int ct = 0; ct < 8; ct++) {
            bf16x8 bl = *(const bf16x8*)(const void*)(pw + (ct * 8 + ks * 2 + 0) * 512);
            bf16x8 br = *(const bf16x8*)(const void*)(pw + (ct * 8 + ks * 2 + 1) * 512);
            acc0[ct] = __builtin_amdgcn_mfma_f32_16x16x32_bf16(a0, bl, acc0[ct], 0, 0, 0);
            acc1[ct] = __builtin_amdgcn_mfma_f32_16x16x32_bf16(a1, bl, acc1[ct], 0, 0, 0);
            acc0[ct] = __builtin_amdgcn_mfma_f32_16x16x32_bf16(x0, br, acc0[ct], 0, 0, 0);
            acc1[ct] = __builtin_amdgcn_mfma_f32_16x16x32_bf16(x1, br, acc1[ct], 0, 0, 0);
        }
    }

    int lr0 = wave * 32 + quad * 4;
#pragma unroll
    for (int ct = 0; ct < 8; ct++) {
        int n = ct * 16 + m;
        float bv = bias[n];
#pragma unroll
        for (int r = 0; r < 4; r++) {
            sh[(lr0 + r) * 132 + n]      = f2b(fmaxf(acc0[ct][r] + bv, 0.f));
            sh[(lr0 + 16 + r) * 132 + n] = f2b(fmaxf(acc1[ct][r] + bv, 0.f));
        }
    }
    __syncthreads();

    const unsigned short* hl0 = sh + (wave * 32 + m) * 132 + koff;
    const unsigned short* hl1 = sh + (wave * 32 + 16 + m) * 132 + koff;
    const unsigned short* pw2 = Wt2 + lane * 8;

    f32x4 al0 = (f32x4){0,0,0,0}, al1 = (f32x4){0,0,0,0};
    f32x4 ar0 = (f32x4){0,0,0,0}, ar1 = (f32x4){0,0,0,0};
#pragma unroll
    for (int ks = 0; ks < 4; ks++) {
        bf16x8 h0 = *(const bf16x8*)(const void*)(hl0 + ks * 32);
        bf16x8 h1 = *(const bf16x8*)(const void*)(hl1 + ks * 32);
        bf16x8 wl = *(const bf16x8*)(const void*)(pw2 + (0 * 4 + ks) * 512);
        bf16x8 wr = *(const bf16x8*)(const void*)(pw2 + (1 * 4 + ks) * 512);
        al0 = __builtin_amdgcn_mfma_f32_16x16x32_bf16(h0, wl, al0, 0, 0, 0);
        al1 = __builtin_amdgcn_mfma_f32_16x16x32_bf16(h1, wl, al1, 0, 0, 0);
        ar0 = __builtin_amdgcn_mfma_f32_16x16x32_bf16(h0, wr, ar0, 0, 0, 0);
        ar1 = __builtin_amdgcn_mfma_f32_16x16x32_bf16(h1, wr, ar1, 0, 0, 0);
    }
    int r0 = row0 + quad * 4;
#pragma unroll
    for (int r = 0; r < 4; r++) {
        trLb[(size_t)(r0 + r) * CLS + m]      = f2b(al0[r]);
        trLb[(size_t)(r0 + 16 + r) * CLS + m] = f2b(al1[r]);
        trR[(size_t)(r0 + r) * CLS + m]       = ar0[r];
        trR[(size_t)(r0 + 16 + r) * CLS + m]  = ar1[r];
    }
}

// ---------------- layer-2: gather-mean trL(bf16, 32B rows) + bias + log_softmax ----------------
__global__ __launch_bounds__(256) void agg2sm_k(const unsigned short* __restrict__ trLb,
                                                const float* __restrict__ trR,
                                                const int* __restrict__ deg,
                                                const int* __restrict__ bucket,
                                                const float* __restrict__ b2,
                                                float* __restrict__ out) {
    int node = blockIdx.x * 4 + (threadIdx.x >> 6);
    int lane = threadIdx.x & 63;
    int r = lane >> 2;          // 0..15: neighbor slot
    int cq = (lane & 3) * 4;    // class group base
    const int* bk = bucket + node * CAP;

    int d_raw = deg[node];
    int nb = min(max(bk[r], 0), N_NODES - 1);
    uint2 v = *(const uint2*)(trLb + (size_t)nb * CLS + cq);
    float4 selfR = *(const float4*)(trR + (size_t)node * CLS + cq);

    int d = min(d_raw, CAP);
    float4 acc = {0.f, 0.f, 0.f, 0.f};
    if (r < d) {
        acc.x += bf2f(v.x & 0xffffu); acc.y += bf2f(v.x >> 16);
        acc.z += bf2f(v.y & 0xffffu); acc.w += bf2f(v.y >> 16);
    }
    for (int j = 16; j < d; j += 16) {
        int idx = j + r;
        bool valid = idx < d;
        int m2 = bk[valid ? idx : 0];
        uint2 w = *(const uint2*)(trLb + (size_t)m2 * CLS + cq);
        if (valid) {
            acc.x += bf2f(w.x & 0xffffu); acc.y += bf2f(w.x >> 16);
            acc.z += bf2f(w.y & 0xffffu); acc.w += bf2f(w.y >> 16);
        }
    }
#pragma unroll
    for (int off = 4; off <= 32; off <<= 1) {
        acc.x += __shfl_xor(acc.x, off);
        acc.y += __shfl_xor(acc.y, off);
        acc.z += __shfl_xor(acc.z, off);
        acc.w += __shfl_xor(acc.w, off);
    }
    float inv = 1.0f / fmaxf((float)d, 1.0f);
    float4 bb = *(const float4*)(b2 + cq);
    float vx = acc.x * inv + selfR.x + bb.x;
    float vy = acc.y * inv + selfR.y + bb.y;
    float vz = acc.z * inv + selfR.z + bb.z;
    float vw = acc.w * inv + selfR.w + bb.w;
    float mx = fmaxf(fmaxf(vx, vy), fmaxf(vz, vw));
    mx = fmaxf(mx, __shfl_xor(mx, 1));
    mx = fmaxf(mx, __shfl_xor(mx, 2));
    float sm = __expf(vx - mx) + __expf(vy - mx) + __expf(vz - mx) + __expf(vw - mx);
    sm += __shfl_xor(sm, 1);
    sm += __shfl_xor(sm, 2);
    float lg = __logf(sm);
    if (r == 0) {
        float4 o = {vx - mx - lg, vy - mx - lg, vz - mx - lg, vw - mx - lg};
        *(float4*)(out + (size_t)node * CLS + cq) = o;
    }
}

// ---------------- launch ----------------

extern "C" void kernel_launch(void* const* d_in, const int* in_sizes, int n_in,
                              void* d_out, int out_size, void* d_ws, size_t ws_size,
                              hipStream_t stream) {
    const float* x   = (const float*)d_in[0];
    const int*   ei  = (const int*)d_in[1];
    const float* W1l = (const float*)d_in[2];
    const float* b1  = (const float*)d_in[3];
    const float* W1r = (const float*)d_in[4];
    const float* W2l = (const float*)d_in[5];
    const float* b2  = (const float*)d_in[6];
    const float* W2r = (const float*)d_in[7];
    float* out = (float*)d_out;

    const int* src = ei;
    const int* dst = ei + N_EDGES;

    char* ws = (char*)d_ws;
    size_t off = 0;
    auto alloc = [&](size_t bytes) { char* p = ws + off; off += (bytes + 127) / 128 * 128; return p; };
    int* deg    = (int*)alloc((size_t)N_NODES * 4);
    int* bucket = (int*)alloc((size_t)N_NODES * CAP * 4);
    unsigned short* xb   = (unsigned short*)alloc((size_t)N_PAD * F * 2);
    unsigned char*  xf8  = (unsigned char*)alloc((size_t)N_PAD * F);
    unsigned short* aggb = (unsigned short*)alloc((size_t)N_PAD * F * 2);
    unsigned short* trLb = (unsigned short*)alloc((size_t)N_PAD * CLS * 2);
    float*          trR  = (float*)alloc((size_t)N_PAD * CLS * 4);
    unsigned short* w1t  = (unsigned short*)alloc((size_t)F * 256 * 2);
    unsigned short* w2t  = (unsigned short*)alloc((size_t)32 * F * 2);

    init_k<<<12743, 256, 0, stream>>>(deg, x, xb, (unsigned int*)xf8,
                                      W1l, W1r, W2l, W2r, w1t, w2t);
    fill_k<<<(N_EDGES + 255) / 256, 256, 0, stream>>>(src, dst, deg, bucket);
    agg_b_k<<<N_NODES / 4, 256, 0, stream>>>(xf8, deg, bucket, aggb);
    gemm_fused<<<N_PAD / 128, 256, 0, stream>>>(aggb, xb, w1t, b1, w2t, trLb, trR);
    agg2sm_k<<<N_NODES / 4, 256, 0, stream>>>(trLb, trR, deg, bucket, b2, out);
}

// Round 11
// 221.895 us; speedup vs baseline: 1.0262x; 1.0262x over previous
//
#include <hip/hip_runtime.h>
#include <cstdint>

#define N_NODES 100000
#define N_PAD 100096   // padded row capacity (multiple of 128)
#define N_EDGES 600000
#define F 128
#define CLS 16
#define CAP 64         // max neighbors stored per node (Poisson(6): P(>=64) ~ 1e-40)

typedef short bf16x8 __attribute__((ext_vector_type(8)));
typedef float f32x4 __attribute__((ext_vector_type(4)));

__device__ inline float bf2f(unsigned int lo16) { return __uint_as_float(lo16 << 16); }
__device__ inline unsigned short f2b(float f) {
    unsigned int u = __float_as_uint(f);
    return (unsigned short)((u + 0x7fffu + ((u >> 16) & 1u)) >> 16);
}

// ---------------- init: zero deg + cast x->bf16 + weight prep (frag order) ----------------
__global__ __launch_bounds__(256) void init_k(int* __restrict__ deg,
                                              const float* __restrict__ x,
                                              unsigned short* __restrict__ xb,
                                              const float* __restrict__ W1l,
                                              const float* __restrict__ W1r,
                                              const float* __restrict__ W2l,
                                              const float* __restrict__ W2r,
                                              unsigned short* __restrict__ w1t,
                                              unsigned short* __restrict__ w2t) {
    int b = blockIdx.x;
    if (b < 98) {
        int i = b * 1024 + threadIdx.x * 4;
#pragma unroll
        for (int k = 0; k < 4; k++)
            if (i + k < N_NODES) deg[i + k] = 0;
    } else if (b < 12598) {
        int i = (b - 98) * 256 + threadIdx.x;
        if (i < N_NODES * F / 4) {
            float4 v = ((const float4*)x)[i];
            ushort4 o;
            o.x = f2b(v.x); o.y = f2b(v.y); o.z = f2b(v.z); o.w = f2b(v.w);
            ((ushort4*)xb)[i] = o;
        }
    } else if (b < 12726) {
        int idx = (b - 12598) * 256 + threadIdx.x;  // 32768: (n,k) n<128, k<256
        int n = idx >> 8, k = idx & 255;
        float v = (k < F) ? W1l[k * F + n] : W1r[(k - F) * F + n];
        int ct = n >> 4, m = n & 15;
        int half = k >> 7, ks = (k >> 5) & 3, quad = (k >> 3) & 3, j = k & 7;
        w1t[(ct * 8 + ks * 2 + half) * 512 + (quad * 16 + m) * 8 + j] = f2b(v);
    } else {
        int idx = (b - 12726) * 256 + threadIdx.x;  // 4096: (n,k) n<32, k<128
        if (idx < 32 * F) {
            int n = idx >> 7, k = idx & 127;
            float v = (n < CLS) ? W2l[k * CLS + n] : W2r[k * CLS + (n - CLS)];
            int tile = n >> 4, m = n & 15;
            int ks = (k >> 5) & 3, quad = (k >> 3) & 3, j = k & 7;
            w2t[(tile * 4 + ks) * 512 + (quad * 16 + m) * 8 + j] = f2b(v);
        }
    }
}

// ---------------- fill: histogram + bucket append in one pass ----------------
__global__ void fill_k(const int* __restrict__ src, const int* __restrict__ dst,
                       int* __restrict__ deg, int* __restrict__ bucket) {
    int e = blockIdx.x * blockDim.x + threadIdx.x;
    if (e < N_EDGES) {
        int d = dst[e];
        int slot = atomicAdd(&deg[d], 1);
        if (slot < CAP) bucket[d * CAP + slot] = src[e];
    }
}

// ---------------- layer-1 mean aggregation: one node per 16-lane group ----------------
// lane c owns feats c*8..c*8+7 (16B). 8 clamped speculative gathers per batch,
// masked accumulate, no cross-lane reduction. 4 nodes/wave, 32 gathers in flight.
__global__ __launch_bounds__(256) void agg_b_k(const unsigned short* __restrict__ feat,
                                               const int* __restrict__ deg,
                                               const int* __restrict__ bucket,
                                               unsigned short* __restrict__ outagg) {
    int tid = threadIdx.x;
    int node = blockIdx.x * 16 + (tid >> 4);
    int f8 = (tid & 15) * 8;
    const int* bk = bucket + node * CAP;

    int d_raw = deg[node];
    float acc[8] = {0.f, 0.f, 0.f, 0.f, 0.f, 0.f, 0.f, 0.f};
    int d = min(d_raw, CAP);

    for (int j0 = 0; j0 < d; j0 += 8) {
        int4 b0 = *(const int4*)(bk + j0);       // uniform within group -> broadcast
        int4 b1 = *(const int4*)(bk + j0 + 4);
        int n0 = min(max(b0.x, 0), N_NODES - 1);
        int n1 = min(max(b0.y, 0), N_NODES - 1);
        int n2 = min(max(b0.z, 0), N_NODES - 1);
        int n3 = min(max(b0.w, 0), N_NODES - 1);
        int n4 = min(max(b1.x, 0), N_NODES - 1);
        int n5 = min(max(b1.y, 0), N_NODES - 1);
        int n6 = min(max(b1.z, 0), N_NODES - 1);
        int n7 = min(max(b1.w, 0), N_NODES - 1);
        uint4 v0 = *(const uint4*)(feat + (size_t)n0 * F + f8);
        uint4 v1 = *(const uint4*)(feat + (size_t)n1 * F + f8);
        uint4 v2 = *(const uint4*)(feat + (size_t)n2 * F + f8);
        uint4 v3 = *(const uint4*)(feat + (size_t)n3 * F + f8);
        uint4 v4 = *(const uint4*)(feat + (size_t)n4 * F + f8);
        uint4 v5 = *(const uint4*)(feat + (size_t)n5 * F + f8);
        uint4 v6 = *(const uint4*)(feat + (size_t)n6 * F + f8);
        uint4 v7 = *(const uint4*)(feat + (size_t)n7 * F + f8);
#define ACC8(vv) { \
    acc[0] += bf2f((vv).x & 0xffffu); acc[1] += bf2f((vv).x >> 16); \
    acc[2] += bf2f((vv).y & 0xffffu); acc[3] += bf2f((vv).y >> 16); \
    acc[4] += bf2f((vv).z & 0xffffu); acc[5] += bf2f((vv).z >> 16); \
    acc[6] += bf2f((vv).w & 0xffffu); acc[7] += bf2f((vv).w >> 16); }
        int rem = d - j0;
        if (rem > 0) ACC8(v0);
        if (rem > 1) ACC8(v1);
        if (rem > 2) ACC8(v2);
        if (rem > 3) ACC8(v3);
        if (rem > 4) ACC8(v4);
        if (rem > 5) ACC8(v5);
        if (rem > 6) ACC8(v6);
        if (rem > 7) ACC8(v7);
#undef ACC8
    }
    float inv = 1.0f / fmaxf((float)d, 1.0f);
    uint4 o;
    o.x = (unsigned int)f2b(acc[0] * inv) | ((unsigned int)f2b(acc[1] * inv) << 16);
    o.y = (unsigned int)f2b(acc[2] * inv) | ((unsigned int)f2b(acc[3] * inv) << 16);
    o.z = (unsigned int)f2b(acc[4] * inv) | ((unsigned int)f2b(acc[5] * inv) << 16);
    o.w = (unsigned int)f2b(acc[6] * inv) | ((unsigned int)f2b(acc[7] * inv) << 16);
    *(uint4*)(outagg + (size_t)node * F + f8) = o;
}

// ---------------- FUSED GEMM: H=relu(A@W1l+X@W1r+b1); trL(bf16)=H@W2l, trR(f32)=H@W2r ----------------
__global__ __launch_bounds__(256) void gemm_fused(const unsigned short* __restrict__ Ab,
                                                  const unsigned short* __restrict__ Xb,
                                                  const unsigned short* __restrict__ Wt,
                                                  const float* __restrict__ bias,
                                                  const unsigned short* __restrict__ Wt2,
                                                  unsigned short* __restrict__ trLb,
                                                  float* __restrict__ trR) {
    __shared__ unsigned short sh[128 * 132];  // H tile, padded
    int tid = threadIdx.x;
    int wave = tid >> 6, lane = tid & 63;
    int row0 = blockIdx.x * 128 + wave * 32;
    int m = lane & 15, quad = lane >> 4;
    int koff = quad * 8;

    const unsigned short* pa0 = Ab + (size_t)(row0 + m) * F + koff;
    const unsigned short* pa1 = pa0 + 16 * F;
    const unsigned short* px0 = Xb + (size_t)(row0 + m) * F + koff;
    const unsigned short* px1 = px0 + 16 * F;
    const unsigned short* pw = Wt + lane * 8;   // + frag*512

    f32x4 acc0[8], acc1[8];
#pragma unroll
    for (int ct = 0; ct < 8; ct++) { acc0[ct] = (f32x4){0,0,0,0}; acc1[ct] = (f32x4){0,0,0,0}; }

#pragma unroll
    for (int ks = 0; ks < 4; ks++) {
        bf16x8 a0 = *(const bf16x8*)(const void*)(pa0 + ks * 32);
        bf16x8 a1 = *(const bf16x8*)(const void*)(pa1 + ks * 32);
        bf16x8 x0 = *(const bf16x8*)(const void*)(px0 + ks * 32);
        bf16x8 x1 = *(const bf16x8*)(const void*)(px1 + ks * 32);
#pragma unroll
        for (int ct = 0; ct < 8; ct++) {
            bf16x8 bl = *(const bf16x8*)(const void*)(pw + (ct * 8 + ks * 2 + 0) * 512);
            bf16x8 br = *(const bf16x8*)(const void*)(pw + (ct * 8 + ks * 2 + 1) * 512);
            acc0[ct] = __builtin_amdgcn_mfma_f32_16x16x32_bf16(a0, bl, acc0[ct], 0, 0, 0);
            acc1[ct] = __builtin_amdgcn_mfma_f32_16x16x32_bf16(a1, bl, acc1[ct], 0, 0, 0);
            acc0[ct] = __builtin_amdgcn_mfma_f32_16x16x32_bf16(x0, br, acc0[ct], 0, 0, 0);
            acc1[ct] = __builtin_amdgcn_mfma_f32_16x16x32_bf16(x1, br, acc1[ct], 0, 0, 0);
        }
    }

    int lr0 = wave * 32 + quad * 4;
#pragma unroll
    for (int ct = 0; ct < 8; ct++) {
        int n = ct * 16 + m;
        float bv = bias[n];
#pragma unroll
        for (int r = 0; r < 4; r++) {
            sh[(lr0 + r) * 132 + n]      = f2b(fmaxf(acc0[ct][r] + bv, 0.f));
            sh[(lr0 + 16 + r) * 132 + n] = f2b(fmaxf(acc1[ct][r] + bv, 0.f));
        }
    }
    __syncthreads();

    const unsigned short* hl0 = sh + (wave * 32 + m) * 132 + koff;
    const unsigned short* hl1 = sh + (wave * 32 + 16 + m) * 132 + koff;
    const unsigned short* pw2 = Wt2 + lane * 8;

    f32x4 al0 = (f32x4){0,0,0,0}, al1 = (f32x4){0,0,0,0};
    f32x4 ar0 = (f32x4){0,0,0,0}, ar1 = (f32x4){0,0,0,0};
#pragma unroll
    for (int ks = 0; ks < 4; ks++) {
        bf16x8 h0 = *(const bf16x8*)(const void*)(hl0 + ks * 32);
        bf16x8 h1 = *(const bf16x8*)(const void*)(hl1 + ks * 32);
        bf16x8 wl = *(const bf16x8*)(const void*)(pw2 + (0 * 4 + ks) * 512);
        bf16x8 wr = *(const bf16x8*)(const void*)(pw2 + (1 * 4 + ks) * 512);
        al0 = __builtin_amdgcn_mfma_f32_16x16x32_bf16(h0, wl, al0, 0, 0, 0);
        al1 = __builtin_amdgcn_mfma_f32_16x16x32_bf16(h1, wl, al1, 0, 0, 0);
        ar0 = __builtin_amdgcn_mfma_f32_16x16x32_bf16(h0, wr, ar0, 0, 0, 0);
        ar1 = __builtin_amdgcn_mfma_f32_16x16x32_bf16(h1, wr, ar1, 0, 0, 0);
    }
    int r0 = row0 + quad * 4;
#pragma unroll
    for (int r = 0; r < 4; r++) {
        trLb[(size_t)(r0 + r) * CLS + m]      = f2b(al0[r]);
        trLb[(size_t)(r0 + 16 + r) * CLS + m] = f2b(al1[r]);
        trR[(size_t)(r0 + r) * CLS + m]       = ar0[r];
        trR[(size_t)(r0 + 16 + r) * CLS + m]  = ar1[r];
    }
}

// ---------------- layer-2: gather-mean trL(bf16, 32B rows) + bias + log_softmax ----------------
__global__ __launch_bounds__(256) void agg2sm_k(const unsigned short* __restrict__ trLb,
                                                const float* __restrict__ trR,
                                                const int* __restrict__ deg,
                                                const int* __restrict__ bucket,
                                                const float* __restrict__ b2,
                                                float* __restrict__ out) {
    int node = blockIdx.x * 4 + (threadIdx.x >> 6);
    int lane = threadIdx.x & 63;
    int r = lane >> 2;          // 0..15: neighbor slot
    int cq = (lane & 3) * 4;    // class group base
    const int* bk = bucket + node * CAP;

    int d_raw = deg[node];
    int nb = min(max(bk[r], 0), N_NODES - 1);
    uint2 v = *(const uint2*)(trLb + (size_t)nb * CLS + cq);
    float4 selfR = *(const float4*)(trR + (size_t)node * CLS + cq);

    int d = min(d_raw, CAP);
    float4 acc = {0.f, 0.f, 0.f, 0.f};
    if (r < d) {
        acc.x += bf2f(v.x & 0xffffu); acc.y += bf2f(v.x >> 16);
        acc.z += bf2f(v.y & 0xffffu); acc.w += bf2f(v.y >> 16);
    }
    for (int j = 16; j < d; j += 16) {
        int idx = j + r;
        bool valid = idx < d;
        int m2 = bk[valid ? idx : 0];
        uint2 w = *(const uint2*)(trLb + (size_t)m2 * CLS + cq);
        if (valid) {
            acc.x += bf2f(w.x & 0xffffu); acc.y += bf2f(w.x >> 16);
            acc.z += bf2f(w.y & 0xffffu); acc.w += bf2f(w.y >> 16);
        }
    }
#pragma unroll
    for (int off = 4; off <= 32; off <<= 1) {
        acc.x += __shfl_xor(acc.x, off);
        acc.y += __shfl_xor(acc.y, off);
        acc.z += __shfl_xor(acc.z, off);
        acc.w += __shfl_xor(acc.w, off);
    }
    float inv = 1.0f / fmaxf((float)d, 1.0f);
    float4 bb = *(const float4*)(b2 + cq);
    float vx = acc.x * inv + selfR.x + bb.x;
    float vy = acc.y * inv + selfR.y + bb.y;
    float vz = acc.z * inv + selfR.z + bb.z;
    float vw = acc.w * inv + selfR.w + bb.w;
    float mx = fmaxf(fmaxf(vx, vy), fmaxf(vz, vw));
    mx = fmaxf(mx, __shfl_xor(mx, 1));
    mx = fmaxf(mx, __shfl_xor(mx, 2));
    float sm = __expf(vx - mx) + __expf(vy - mx) + __expf(vz - mx) + __expf(vw - mx);
    sm += __shfl_xor(sm, 1);
    sm += __shfl_xor(sm, 2);
    float lg = __logf(sm);
    if (r == 0) {
        float4 o = {vx - mx - lg, vy - mx - lg, vz - mx - lg, vw - mx - lg};
        *(float4*)(out + (size_t)node * CLS + cq) = o;
    }
}

// ---------------- launch ----------------

extern "C" void kernel_launch(void* const* d_in, const int* in_sizes, int n_in,
                              void* d_out, int out_size, void* d_ws, size_t ws_size,
                              hipStream_t stream) {
    const float* x   = (const float*)d_in[0];
    const int*   ei  = (const int*)d_in[1];
    const float* W1l = (const float*)d_in[2];
    const float* b1  = (const float*)d_in[3];
    const float* W1r = (const float*)d_in[4];
    const float* W2l = (const float*)d_in[5];
    const float* b2  = (const float*)d_in[6];
    const float* W2r = (const float*)d_in[7];
    float* out = (float*)d_out;

    const int* src = ei;
    const int* dst = ei + N_EDGES;

    char* ws = (char*)d_ws;
    size_t off = 0;
    auto alloc = [&](size_t bytes) { char* p = ws + off; off += (bytes + 127) / 128 * 128; return p; };
    int* deg    = (int*)alloc((size_t)N_NODES * 4);
    int* bucket = (int*)alloc((size_t)N_NODES * CAP * 4);
    unsigned short* xb   = (unsigned short*)alloc((size_t)N_PAD * F * 2);
    unsigned short* aggb = (unsigned short*)alloc((size_t)N_PAD * F * 2);
    unsigned short* trLb = (unsigned short*)alloc((size_t)N_PAD * CLS * 2);
    float*          trR  = (float*)alloc((size_t)N_PAD * CLS * 4);
    unsigned short* w1t  = (unsigned short*)alloc((size_t)F * 256 * 2);
    unsigned short* w2t  = (unsigned short*)alloc((size_t)32 * F * 2);

    init_k<<<12743, 256, 0, stream>>>(deg, x, xb, W1l, W1r, W2l, W2r, w1t, w2t);
    fill_k<<<(N_EDGES + 255) / 256, 256, 0, stream>>>(src, dst, deg, bucket);
    agg_b_k<<<N_NODES / 16, 256, 0, stream>>>(xb, deg, bucket, aggb);
    gemm_fused<<<N_PAD / 128, 256, 0, stream>>>(aggb, xb, w1t, b1, w2t, trLb, trR);
    agg2sm_k<<<N_NODES / 4, 256, 0, stream>>>(trLb, trR, deg, bucket, b2, out);
}

// Round 12
// 220.226 us; speedup vs baseline: 1.0340x; 1.0076x over previous
//
#include <hip/hip_runtime.h>
#include <cstdint>

#define N_NODES 100000
#define N_PAD 100096   // padded row capacity (multiple of 128)
#define N_EDGES 600000
#define F 128
#define CLS 16
#define CAP 32         // max neighbors stored (Poisson(6): P(>=32) ~ 1e-14 per node)

typedef short bf16x8 __attribute__((ext_vector_type(8)));
typedef float f32x4 __attribute__((ext_vector_type(4)));

__device__ inline float bf2f(unsigned int lo16) { return __uint_as_float(lo16 << 16); }
__device__ inline unsigned short f2b(float f) {
    unsigned int u = __float_as_uint(f);
    return (unsigned short)((u + 0x7fffu + ((u >> 16) & 1u)) >> 16);
}

// ---------------- init: zero deg + cast x->bf16 + weight prep (frag order) ----------------
__global__ __launch_bounds__(256) void init_k(int* __restrict__ deg,
                                              const float* __restrict__ x,
                                              unsigned short* __restrict__ xb,
                                              const float* __restrict__ W1l,
                                              const float* __restrict__ W1r,
                                              const float* __restrict__ W2l,
                                              const float* __restrict__ W2r,
                                              unsigned short* __restrict__ w1t,
                                              unsigned short* __restrict__ w2t) {
    int b = blockIdx.x;
    if (b < 98) {
        int i = b * 1024 + threadIdx.x * 4;
#pragma unroll
        for (int k = 0; k < 4; k++)
            if (i + k < N_NODES) deg[i + k] = 0;
    } else if (b < 12598) {
        int i = (b - 98) * 256 + threadIdx.x;
        if (i < N_NODES * F / 4) {
            float4 v = ((const float4*)x)[i];
            ushort4 o;
            o.x = f2b(v.x); o.y = f2b(v.y); o.z = f2b(v.z); o.w = f2b(v.w);
            ((ushort4*)xb)[i] = o;
        }
    } else if (b < 12726) {
        int idx = (b - 12598) * 256 + threadIdx.x;  // 32768: (n,k) n<128, k<256
        int n = idx >> 8, k = idx & 255;
        float v = (k < F) ? W1l[k * F + n] : W1r[(k - F) * F + n];
        int ct = n >> 4, m = n & 15;
        int half = k >> 7, ks = (k >> 5) & 3, quad = (k >> 3) & 3, j = k & 7;
        w1t[(ct * 8 + ks * 2 + half) * 512 + (quad * 16 + m) * 8 + j] = f2b(v);
    } else {
        int idx = (b - 12726) * 256 + threadIdx.x;  // 4096: (n,k) n<32, k<128
        if (idx < 32 * F) {
            int n = idx >> 7, k = idx & 127;
            float v = (n < CLS) ? W2l[k * CLS + n] : W2r[k * CLS + (n - CLS)];
            int tile = n >> 4, m = n & 15;
            int ks = (k >> 5) & 3, quad = (k >> 3) & 3, j = k & 7;
            w2t[(tile * 4 + ks) * 512 + (quad * 16 + m) * 8 + j] = f2b(v);
        }
    }
}

// ---------------- fill: histogram + bucket append in one pass ----------------
__global__ void fill_k(const int* __restrict__ src, const int* __restrict__ dst,
                       int* __restrict__ deg, int* __restrict__ bucket) {
    int e = blockIdx.x * blockDim.x + threadIdx.x;
    if (e < N_EDGES) {
        int d = dst[e];
        int slot = atomicAdd(&deg[d], 1);
        if (slot < CAP) bucket[d * CAP + slot] = src[e];
    }
}

// ---------------- layer-1 mean aggregation: one node per 16-lane group ----------------
// Straight-line 12-slot speculative batch (clamped poison -> row 0, L1-hot),
// masked accumulate; rare tail (P(d>12)~0.9%/node) steps by 4. No reductions.
__global__ __launch_bounds__(256) void agg_b_k(const unsigned short* __restrict__ feat,
                                               const int* __restrict__ deg,
                                               const int* __restrict__ bucket,
                                               unsigned short* __restrict__ outagg) {
    int tid = threadIdx.x;
    int node = blockIdx.x * 16 + (tid >> 4);
    int f8 = (tid & 15) * 8;
    const int* bk = bucket + node * CAP;

    int d_raw = deg[node];
    int4 b0 = *(const int4*)(bk);        // uniform within group -> broadcast
    int4 b1 = *(const int4*)(bk + 4);
    int4 b2 = *(const int4*)(bk + 8);
    int n0  = min(max(b0.x, 0), N_NODES - 1);
    int n1  = min(max(b0.y, 0), N_NODES - 1);
    int n2  = min(max(b0.z, 0), N_NODES - 1);
    int n3  = min(max(b0.w, 0), N_NODES - 1);
    int n4  = min(max(b1.x, 0), N_NODES - 1);
    int n5  = min(max(b1.y, 0), N_NODES - 1);
    int n6  = min(max(b1.z, 0), N_NODES - 1);
    int n7  = min(max(b1.w, 0), N_NODES - 1);
    int n8  = min(max(b2.x, 0), N_NODES - 1);
    int n9  = min(max(b2.y, 0), N_NODES - 1);
    int n10 = min(max(b2.z, 0), N_NODES - 1);
    int n11 = min(max(b2.w, 0), N_NODES - 1);
    uint4 v0  = *(const uint4*)(feat + (size_t)n0 * F + f8);
    uint4 v1  = *(const uint4*)(feat + (size_t)n1 * F + f8);
    uint4 v2  = *(const uint4*)(feat + (size_t)n2 * F + f8);
    uint4 v3  = *(const uint4*)(feat + (size_t)n3 * F + f8);
    uint4 v4  = *(const uint4*)(feat + (size_t)n4 * F + f8);
    uint4 v5  = *(const uint4*)(feat + (size_t)n5 * F + f8);
    uint4 v6  = *(const uint4*)(feat + (size_t)n6 * F + f8);
    uint4 v7  = *(const uint4*)(feat + (size_t)n7 * F + f8);
    uint4 v8  = *(const uint4*)(feat + (size_t)n8 * F + f8);
    uint4 v9  = *(const uint4*)(feat + (size_t)n9 * F + f8);
    uint4 v10 = *(const uint4*)(feat + (size_t)n10 * F + f8);
    uint4 v11 = *(const uint4*)(feat + (size_t)n11 * F + f8);

    int d = min(d_raw, CAP);
    float acc[8] = {0.f, 0.f, 0.f, 0.f, 0.f, 0.f, 0.f, 0.f};
#define ACC8(vv) { \
    acc[0] += bf2f((vv).x & 0xffffu); acc[1] += bf2f((vv).x >> 16); \
    acc[2] += bf2f((vv).y & 0xffffu); acc[3] += bf2f((vv).y >> 16); \
    acc[4] += bf2f((vv).z & 0xffffu); acc[5] += bf2f((vv).z >> 16); \
    acc[6] += bf2f((vv).w & 0xffffu); acc[7] += bf2f((vv).w >> 16); }
    if (d > 0)  ACC8(v0);
    if (d > 1)  ACC8(v1);
    if (d > 2)  ACC8(v2);
    if (d > 3)  ACC8(v3);
    if (d > 4)  ACC8(v4);
    if (d > 5)  ACC8(v5);
    if (d > 6)  ACC8(v6);
    if (d > 7)  ACC8(v7);
    if (d > 8)  ACC8(v8);
    if (d > 9)  ACC8(v9);
    if (d > 10) ACC8(v10);
    if (d > 11) ACC8(v11);
    // rare tail: d in (12, 32]
    for (int j0 = 12; j0 < d; j0 += 4) {
        int4 bb = *(const int4*)(bk + j0);
        int m0 = min(max(bb.x, 0), N_NODES - 1);
        int m1 = min(max(bb.y, 0), N_NODES - 1);
        int m2 = min(max(bb.z, 0), N_NODES - 1);
        int m3 = min(max(bb.w, 0), N_NODES - 1);
        uint4 w0 = *(const uint4*)(feat + (size_t)m0 * F + f8);
        uint4 w1 = *(const uint4*)(feat + (size_t)m1 * F + f8);
        uint4 w2 = *(const uint4*)(feat + (size_t)m2 * F + f8);
        uint4 w3 = *(const uint4*)(feat + (size_t)m3 * F + f8);
        int rem = d - j0;
        if (rem > 0) ACC8(w0);
        if (rem > 1) ACC8(w1);
        if (rem > 2) ACC8(w2);
        if (rem > 3) ACC8(w3);
    }
#undef ACC8
    float inv = 1.0f / fmaxf((float)d, 1.0f);
    uint4 o;
    o.x = (unsigned int)f2b(acc[0] * inv) | ((unsigned int)f2b(acc[1] * inv) << 16);
    o.y = (unsigned int)f2b(acc[2] * inv) | ((unsigned int)f2b(acc[3] * inv) << 16);
    o.z = (unsigned int)f2b(acc[4] * inv) | ((unsigned int)f2b(acc[5] * inv) << 16);
    o.w = (unsigned int)f2b(acc[6] * inv) | ((unsigned int)f2b(acc[7] * inv) << 16);
    *(uint4*)(outagg + (size_t)node * F + f8) = o;
}

// ---------------- FUSED GEMM: H=relu(A@W1l+X@W1r+b1); trL(bf16)=H@W2l, trR(f32)=H@W2r ----------------
__global__ __launch_bounds__(256) void gemm_fused(const unsigned short* __restrict__ Ab,
                                                  const unsigned short* __restrict__ Xb,
                                                  const unsigned short* __restrict__ Wt,
                                                  const float* __restrict__ bias,
                                                  const unsigned short* __restrict__ Wt2,
                                                  unsigned short* __restrict__ trLb,
                                                  float* __restrict__ trR) {
    __shared__ unsigned short sh[128 * 132];  // H tile, padded
    int tid = threadIdx.x;
    int wave = tid >> 6, lane = tid & 63;
    int row0 = blockIdx.x * 128 + wave * 32;
    int m = lane & 15, quad = lane >> 4;
    int koff = quad * 8;

    const unsigned short* pa0 = Ab + (size_t)(row0 + m) * F + koff;
    const unsigned short* pa1 = pa0 + 16 * F;
    const unsigned short* px0 = Xb + (size_t)(row0 + m) * F + koff;
    const unsigned short* px1 = px0 + 16 * F;
    const unsigned short* pw = Wt + lane * 8;   // + frag*512

    f32x4 acc0[8], acc1[8];
#pragma unroll
    for (int ct = 0; ct < 8; ct++) { acc0[ct] = (f32x4){0,0,0,0}; acc1[ct] = (f32x4){0,0,0,0}; }

#pragma unroll
    for (int ks = 0; ks < 4; ks++) {
        bf16x8 a0 = *(const bf16x8*)(const void*)(pa0 + ks * 32);
        bf16x8 a1 = *(const bf16x8*)(const void*)(pa1 + ks * 32);
        bf16x8 x0 = *(const bf16x8*)(const void*)(px0 + ks * 32);
        bf16x8 x1 = *(const bf16x8*)(const void*)(px1 + ks * 32);
#pragma unroll
        for (int ct = 0; ct < 8; ct++) {
            bf16x8 bl = *(const bf16x8*)(const void*)(pw + (ct * 8 + ks * 2 + 0) * 512);
            bf16x8 br = *(const bf16x8*)(const void*)(pw + (ct * 8 + ks * 2 + 1) * 512);
            acc0[ct] = __builtin_amdgcn_mfma_f32_16x16x32_bf16(a0, bl, acc0[ct], 0, 0, 0);
            acc1[ct] = __builtin_amdgcn_mfma_f32_16x16x32_bf16(a1, bl, acc1[ct], 0, 0, 0);
            acc0[ct] = __builtin_amdgcn_mfma_f32_16x16x32_bf16(x0, br, acc0[ct], 0, 0, 0);
            acc1[ct] = __builtin_amdgcn_mfma_f32_16x16x32_bf16(x1, br, acc1[ct], 0, 0, 0);
        }
    }

    int lr0 = wave * 32 + quad * 4;
#pragma unroll
    for (int ct = 0; ct < 8; ct++) {
        int n = ct * 16 + m;
        float bv = bias[n];
#pragma unroll
        for (int r = 0; r < 4; r++) {
            sh[(lr0 + r) * 132 + n]      = f2b(fmaxf(acc0[ct][r] + bv, 0.f));
            sh[(lr0 + 16 + r) * 132 + n] = f2b(fmaxf(acc1[ct][r] + bv, 0.f));
        }
    }
    __syncthreads();

    const unsigned short* hl0 = sh + (wave * 32 + m) * 132 + koff;
    const unsigned short* hl1 = sh + (wave * 32 + 16 + m) * 132 + koff;
    const unsigned short* pw2 = Wt2 + lane * 8;

    f32x4 al0 = (f32x4){0,0,0,0}, al1 = (f32x4){0,0,0,0};
    f32x4 ar0 = (f32x4){0,0,0,0}, ar1 = (f32x4){0,0,0,0};
#pragma unroll
    for (int ks = 0; ks < 4; ks++) {
        bf16x8 h0 = *(const bf16x8*)(const void*)(hl0 + ks * 32);
        bf16x8 h1 = *(const bf16x8*)(const void*)(hl1 + ks * 32);
        bf16x8 wl = *(const bf16x8*)(const void*)(pw2 + (0 * 4 + ks) * 512);
        bf16x8 wr = *(const bf16x8*)(const void*)(pw2 + (1 * 4 + ks) * 512);
        al0 = __builtin_amdgcn_mfma_f32_16x16x32_bf16(h0, wl, al0, 0, 0, 0);
        al1 = __builtin_amdgcn_mfma_f32_16x16x32_bf16(h1, wl, al1, 0, 0, 0);
        ar0 = __builtin_amdgcn_mfma_f32_16x16x32_bf16(h0, wr, ar0, 0, 0, 0);
        ar1 = __builtin_amdgcn_mfma_f32_16x16x32_bf16(h1, wr, ar1, 0, 0, 0);
    }
    int r0 = row0 + quad * 4;
#pragma unroll
    for (int r = 0; r < 4; r++) {
        trLb[(size_t)(r0 + r) * CLS + m]      = f2b(al0[r]);
        trLb[(size_t)(r0 + 16 + r) * CLS + m] = f2b(al1[r]);
        trR[(size_t)(r0 + r) * CLS + m]       = ar0[r];
        trR[(size_t)(r0 + 16 + r) * CLS + m]  = ar1[r];
    }
}

// ---------------- layer-2: gather-mean trL(bf16, 32B rows) + bias + log_softmax ----------------
__global__ __launch_bounds__(256) void agg2sm_k(const unsigned short* __restrict__ trLb,
                                                const float* __restrict__ trR,
                                                const int* __restrict__ deg,
                                                const int* __restrict__ bucket,
                                                const float* __restrict__ b2,
                                                float* __restrict__ out) {
    int node = blockIdx.x * 4 + (threadIdx.x >> 6);
    int lane = threadIdx.x & 63;
    int r = lane >> 2;          // 0..15: neighbor slot
    int cq = (lane & 3) * 4;    // class group base
    const int* bk = bucket + node * CAP;

    int d_raw = deg[node];
    int nb = min(max(bk[r], 0), N_NODES - 1);
    uint2 v = *(const uint2*)(trLb + (size_t)nb * CLS + cq);
    float4 selfR = *(const float4*)(trR + (size_t)node * CLS + cq);

    int d = min(d_raw, CAP);
    float4 acc = {0.f, 0.f, 0.f, 0.f};
    if (r < d) {
        acc.x += bf2f(v.x & 0xffffu); acc.y += bf2f(v.x >> 16);
        acc.z += bf2f(v.y & 0xffffu); acc.w += bf2f(v.y >> 16);
    }
    if (d > 16) {   // single rare tail (d <= 32)
        int idx = 16 + r;
        bool valid = idx < d;
        int m2 = bk[valid ? idx : 0];
        uint2 w = *(const uint2*)(trLb + (size_t)m2 * CLS + cq);
        if (valid) {
            acc.x += bf2f(w.x & 0xffffu); acc.y += bf2f(w.x >> 16);
            acc.z += bf2f(w.y & 0xffffu); acc.w += bf2f(w.y >> 16);
        }
    }
#pragma unroll
    for (int off = 4; off <= 32; off <<= 1) {
        acc.x += __shfl_xor(acc.x, off);
        acc.y += __shfl_xor(acc.y, off);
        acc.z += __shfl_xor(acc.z, off);
        acc.w += __shfl_xor(acc.w, off);
    }
    float inv = 1.0f / fmaxf((float)d, 1.0f);
    float4 bb = *(const float4*)(b2 + cq);
    float vx = acc.x * inv + selfR.x + bb.x;
    float vy = acc.y * inv + selfR.y + bb.y;
    float vz = acc.z * inv + selfR.z + bb.z;
    float vw = acc.w * inv + selfR.w + bb.w;
    float mx = fmaxf(fmaxf(vx, vy), fmaxf(vz, vw));
    mx = fmaxf(mx, __shfl_xor(mx, 1));
    mx = fmaxf(mx, __shfl_xor(mx, 2));
    float sm = __expf(vx - mx) + __expf(vy - mx) + __expf(vz - mx) + __expf(vw - mx);
    sm += __shfl_xor(sm, 1);
    sm += __shfl_xor(sm, 2);
    float lg = __logf(sm);
    if (r == 0) {
        float4 o = {vx - mx - lg, vy - mx - lg, vz - mx - lg, vw - mx - lg};
        *(float4*)(out + (size_t)node * CLS + cq) = o;
    }
}

// ---------------- launch ----------------

extern "C" void kernel_launch(void* const* d_in, const int* in_sizes, int n_in,
                              void* d_out, int out_size, void* d_ws, size_t ws_size,
                              hipStream_t stream) {
    const float* x   = (const float*)d_in[0];
    const int*   ei  = (const int*)d_in[1];
    const float* W1l = (const float*)d_in[2];
    const float* b1  = (const float*)d_in[3];
    const float* W1r = (const float*)d_in[4];
    const float* W2l = (const float*)d_in[5];
    const float* b2  = (const float*)d_in[6];
    const float* W2r = (const float*)d_in[7];
    float* out = (float*)d_out;

    const int* src = ei;
    const int* dst = ei + N_EDGES;

    char* ws = (char*)d_ws;
    size_t off = 0;
    auto alloc = [&](size_t bytes) { char* p = ws + off; off += (bytes + 127) / 128 * 128; return p; };
    int* deg    = (int*)alloc((size_t)N_NODES * 4);
    int* bucket = (int*)alloc((size_t)N_NODES * CAP * 4);
    unsigned short* xb   = (unsigned short*)alloc((size_t)N_PAD * F * 2);
    unsigned short* aggb = (unsigned short*)alloc((size_t)N_PAD * F * 2);
    unsigned short* trLb = (unsigned short*)alloc((size_t)N_PAD * CLS * 2);
    float*          trR  = (float*)alloc((size_t)N_PAD * CLS * 4);
    unsigned short* w1t  = (unsigned short*)alloc((size_t)F * 256 * 2);
    unsigned short* w2t  = (unsigned short*)alloc((size_t)32 * F * 2);

    init_k<<<12743, 256, 0, stream>>>(deg, x, xb, W1l, W1r, W2l, W2r, w1t, w2t);
    fill_k<<<(N_EDGES + 255) / 256, 256, 0, stream>>>(src, dst, deg, bucket);
    agg_b_k<<<N_NODES / 16, 256, 0, stream>>>(xb, deg, bucket, aggb);
    gemm_fused<<<N_PAD / 128, 256, 0, stream>>>(aggb, xb, w1t, b1, w2t, trLb, trR);
    agg2sm_k<<<N_NODES / 4, 256, 0, stream>>>(trLb, trR, deg, bucket, b2, out);
}